// Round 13
// baseline (87.314 us; speedup 1.0000x reference)
//
#include <hip/hip_runtime.h>

typedef _Float16 half8 __attribute__((ext_vector_type(8)));
typedef float f32x16 __attribute__((ext_vector_type(16)));

#define NPTS   4096
#define BATCH  16
#define NREC   (2 * BATCH * NPTS)     // 131072 records
#define NPRE   512                    // pre-kernel blocks
#define NMAIN  1024                   // main blocks: 2 dir x 16 b x 32 j
#define NPART  (NMAIN * 4)            // per-wave partials

// dist(s,o) = |s|^2 + (s.g + q), g = -2o, q = |o|^2, f16 hi/lo split.
// 16-B record/other: R = [ghx,ghy,ghz,glx,gly,glz,qh,ql]. A-frag per K-group:
//   grp0: A=[shx,shy,shz, 0,0,0, 1, 0]       -> sh.gh + qh
//   grp1: A=[slx,sly,slz, shx,shy,shz, 0, 1] -> sl.gh + sh.gl + ql
// (verified exact: R9-R12 absmax 0.0). Sum(|s|^2) over BOTH directions equals
// Sum(q) over all records, so the pre-kernel banks it and main skips ssq.

__global__ __launch_bounds__(256) void chamfer_prep(
    const float* __restrict__ p1, const float* __restrict__ p2,
    half8* __restrict__ rec, float* __restrict__ qsum)
{
    const int gid = blockIdx.x * 256 + threadIdx.x;   // 0..131071
    const int dir = gid >> 16;
    const int rem = gid & 0xFFFF;                     // b*4096 + i
    const float* src = (dir == 0 ? p2 : p1) + (size_t)rem * 3;
    float ox = src[0], oy = src[1], oz = src[2];
    float gx = -2.f * ox, gy = -2.f * oy, gz = -2.f * oz;
    float q  = fmaf(ox, ox, fmaf(oy, oy, oz * oz));
    _Float16 ghx = (_Float16)gx, ghy = (_Float16)gy, ghz = (_Float16)gz;
    half8 r;
    r[0] = ghx; r[1] = ghy; r[2] = ghz;
    r[3] = (_Float16)(gx - (float)ghx);
    r[4] = (_Float16)(gy - (float)ghy);
    r[5] = (_Float16)(gz - (float)ghz);
    _Float16 qh = (_Float16)q;
    r[6] = qh;
    r[7] = (_Float16)(q - (float)qh);
    rec[gid] = r;

    // Block q-sum (= Sum(|s|^2) contribution): shuffle tree + one store.
    float s = q;
#pragma unroll
    for (int off = 32; off > 0; off >>= 1) s += __shfl_down(s, off, 64);
    __shared__ float ws4[4];
    int lane = threadIdx.x & 63, wv = threadIdx.x >> 6;
    if (lane == 0) ws4[wv] = s;
    __syncthreads();
    if (threadIdx.x == 0)
        qsum[blockIdx.x] = ws4[0] + ws4[1] + ws4[2] + ws4[3];
}

// Barrier-free, LDS-free: wave = 32 selves x all 4096 others.
__global__ __launch_bounds__(256, 4) void chamfer_main(
    const float* __restrict__ p1, const float* __restrict__ p2,
    const half8* __restrict__ rec, float* __restrict__ partial)
{
    const int tid  = threadIdx.x;
    const int lane = tid & 63;
    const int n    = lane & 31;
    const int grp  = lane >> 5;
    const int wv   = tid >> 6;          // 0..3
    const int blk  = blockIdx.x;        // 0..1023 = exactly 4/CU
    const int j    = blk & 31;          // self tile of 128
    const int b    = (blk >> 5) & 15;
    const int dir  = blk >> 9;

    const float* selfp = (dir == 0 ? p1 : p2) + (size_t)b * NPTS * 3;

    // A fragment for self s = j*128 + wv*32 + n (verified layout).
    half8 a0;
    {
        const int i0 = (j * 128 + wv * 32 + n) * 3;
        float x = selfp[i0], y = selfp[i0 + 1], z = selfp[i0 + 2];
        _Float16 hx = (_Float16)x, hy = (_Float16)y, hz = (_Float16)z;
        const _Float16 c0 = (_Float16)0.f, c1 = (_Float16)1.f;
        if (grp == 0) {
            a0[0] = hx; a0[1] = hy; a0[2] = hz;
            a0[3] = c0; a0[4] = c0; a0[5] = c0; a0[6] = c1; a0[7] = c0;
        } else {
            a0[0] = (_Float16)(x - (float)hx);
            a0[1] = (_Float16)(y - (float)hy);
            a0[2] = (_Float16)(z - (float)hz);
            a0[3] = hx; a0[4] = hy; a0[5] = hz; a0[6] = c0; a0[7] = c1;
        }
    }

    f32x16 m, zc;
#pragma unroll
    for (int r = 0; r < 16; ++r) { m[r] = 3.4e38f; zc[r] = 0.f; }

    // Stream all 4096 records straight from global (L1/L2-resident 64 KB).
    const half8* rp = rec + ((size_t)(dir * BATCH + b) << 12) + n;
#pragma unroll 4
    for (int g = 0; g < 64; ++g) {      // 2 tiles of 32 others per iter
        half8 b0 = rp[(2 * g + 0) * 32];
        half8 b1 = rp[(2 * g + 1) * 32];
        f32x16 o0 = __builtin_amdgcn_mfma_f32_32x32x16_f16(a0, b0, zc, 0, 0, 0);
        f32x16 o1 = __builtin_amdgcn_mfma_f32_32x32x16_f16(a0, b1, zc, 0, 0, 0);
#pragma unroll
        for (int r = 0; r < 16; ++r)
            m[r] = fminf(fminf(o0[r], o1[r]), m[r]);   // v_min3_f32
    }

    // Epilogue (verified R10): col-min within 32-lane halves, rowsum,
    // cross-group fold; lane 0 stores the wave partial. No barriers.
#pragma unroll
    for (int mask = 1; mask <= 16; mask <<= 1) {
#pragma unroll
        for (int r = 0; r < 16; ++r)
            m[r] = fminf(m[r], __shfl_xor((float)m[r], mask, 64));
    }
    float rowsum = 0.f;
#pragma unroll
    for (int r = 0; r < 16; ++r) rowsum += m[r];
    rowsum += __shfl_xor(rowsum, 32, 64);   // other K-group's 16 rows

    if (lane == 0) partial[blk * 4 + wv] = rowsum;
}

__global__ __launch_bounds__(256) void chamfer_reduce(
    const float* __restrict__ partial, const float* __restrict__ qsum,
    float* __restrict__ out)
{
    float s = 0.f;
    for (int i = threadIdx.x; i < NPART; i += 256) s += partial[i];
    for (int i = threadIdx.x; i < NPRE; i += 256) s += qsum[i];
#pragma unroll
    for (int off = 32; off > 0; off >>= 1) s += __shfl_down(s, off, 64);
    __shared__ float ws4[4];
    int lane = threadIdx.x & 63, wv = threadIdx.x >> 6;
    if (lane == 0) ws4[wv] = s;
    __syncthreads();
    if (threadIdx.x == 0)
        out[0] = (ws4[0] + ws4[1] + ws4[2] + ws4[3]) * (1.0f / BATCH);
}

extern "C" void kernel_launch(void* const* d_in, const int* in_sizes, int n_in,
                              void* d_out, int out_size, void* d_ws, size_t ws_size,
                              hipStream_t stream) {
    const float* p1 = (const float*)d_in[0];
    const float* p2 = (const float*)d_in[1];
    float* out = (float*)d_out;
    // d_ws layout: [0, 2MB) records | [2MB, +16KB) partials | then qsums.
    half8* rec     = (half8*)d_ws;
    float* partial = (float*)((char*)d_ws + (size_t)NREC * 16);
    float* qsum    = partial + NPART;

    chamfer_prep<<<dim3(NPRE), dim3(256), 0, stream>>>(p1, p2, rec, qsum);
    chamfer_main<<<dim3(NMAIN), dim3(256), 0, stream>>>(p1, p2, rec, partial);
    chamfer_reduce<<<dim3(1), dim3(256), 0, stream>>>(partial, qsum, out);
}